// Round 9
// baseline (448.323 us; speedup 1.0000x reference)
//
#include <hip/hip_runtime.h>

#define N 768
#define H 128
#define NM1 767
#define LDSW (H + 4)   // row stride 132: 4-bank row shift; uu broadcast, vv 2-way (free)
#define MAGIC 0x5EC7BEEFu
#define NPROD 64       // producer blocks
#define PR 12          // U/Vb rows per producer
#define TI 32
#define TJ 32
#define NTJ 24         // 768/32

union Smem {
  float zsh[PR][H];                                          // producer
  struct { float ush[TI * LDSW]; float vsh[TJ * LDSW]; } b;  // consumer (33.8 KB -> 4 blk/CU)
};

__global__ __launch_bounds__(256) void fused_pc3(
    const float* __restrict__ z, const float* __restrict__ W1,
    const float* __restrict__ b1, const float* __restrict__ w2,
    const float* __restrict__ b2, float* __restrict__ U,
    float* __restrict__ Vb, unsigned int* __restrict__ flags,
    float* __restrict__ out) {
  __shared__ Smem sm;
  const int t = threadIdx.x;
  const int blk = blockIdx.x;

  if (blk < NPROD) {
    // ---------- Producer: U/Vb rows [PR*blk, PR*blk+PR) ----------
    const int r0 = blk * PR;
    for (int l = t; l < PR * (H / 4); l += 256) {
      const int r = l >> 5, c4 = l & 31;
      ((float4*)sm.zsh[r])[c4] = ((const float4*)(z + (size_t)(r0 + r) * H))[c4];
    }
    __syncthreads();
    const int k = t & (H - 1);       // output channel (coalesced stores across lanes)
    const int half = t >> 7;         // 0 -> U, 1 -> Vb (wave-uniform)
    const float* __restrict__ wrow = W1 + (size_t)k * (2 * H) + half * H;
    float a[PR] = {};
    for (int m = 0; m < H; m += 4) {          // no unroll pragma: keep VGPR low (R2 lesson)
      const float4 w = *(const float4*)(wrow + m);
#pragma unroll
      for (int r = 0; r < PR; ++r) {          // fully unrolled -> static a[] indexing
        const float4 zq = *(const float4*)&sm.zsh[r][m];
        a[r] = fmaf(w.x, zq.x, a[r]); a[r] = fmaf(w.y, zq.y, a[r]);
        a[r] = fmaf(w.z, zq.z, a[r]); a[r] = fmaf(w.w, zq.w, a[r]);
      }
    }
    const float bias = half ? b1[k] : 0.f;
    float* dst = half ? Vb : U;
#pragma unroll
    for (int r = 0; r < PR; ++r) {
      // relaxed agent-scope store: write-through to coherence point, no dirty L2,
      // no fence needed -> no L2 writeback storm (the R7/R8 killer theory).
      unsigned int* p = (unsigned int*)&dst[(size_t)(r0 + r) * H + k];
      __hip_atomic_store(p, __float_as_uint(a[r] + bias),
                         __ATOMIC_RELAXED, __HIP_MEMORY_SCOPE_AGENT);
    }
    asm volatile("s_waitcnt vmcnt(0)" ::: "memory");  // this wave's stores are visible
    __syncthreads();                                   // join all 4 waves
    if (t == 0)
      __hip_atomic_store(&flags[blk], MAGIC, __ATOMIC_RELAXED, __HIP_MEMORY_SCOPE_AGENT);
    if (blk == NPROD - 1 && t == 0) {
      // master-aggregator: 63 acquire-polls on ONE thread, then one release flag
      for (int q = 0; q < NPROD - 1; ++q)
        while (__hip_atomic_load(&flags[q], __ATOMIC_ACQUIRE,
                                 __HIP_MEMORY_SCOPE_AGENT) != MAGIC)
          __builtin_amdgcn_s_sleep(2);
      __hip_atomic_store(&flags[NPROD], MAGIC, __ATOMIC_RELEASE, __HIP_MEMORY_SCOPE_AGENT);
    }
    return;
  }

  // ---------- Consumer: 32x32 tile, 2x2 regs (R6-verified phase B) ----------
  const int tile = blk - NPROD;
  const int bi = (tile / NTJ) * TI;
  const int bj = (tile % NTJ) * TJ;
  if (t == 0) {
    // single acquire per block: ordering + L2 invalidate (covers the staged loads)
    while (__hip_atomic_load(&flags[NPROD], __ATOMIC_ACQUIRE,
                             __HIP_MEMORY_SCOPE_AGENT) != MAGIC)
      __builtin_amdgcn_s_sleep(8);
  }
  __syncthreads();

#pragma unroll
  for (int l = t; l < TI * (H / 4); l += 256) {
    const int r = l >> 5, c4 = l & 31;
    *(float4*)&sm.b.ush[r * LDSW + c4 * 4] = ((const float4*)(U  + (size_t)(bi + r) * H))[c4];
    *(float4*)&sm.b.vsh[r * LDSW + c4 * 4] = ((const float4*)(Vb + (size_t)(bj + r) * H))[c4];
  }
  __syncthreads();
  const int tx = t & 15, ty = t >> 4;
  float acc[2][2] = {};
#pragma unroll 8
  for (int k = 0; k < H; k += 4) {
    const float4 w = *(const float4*)(w2 + k);   // uniform -> scalar load
    float4 uu[2], vv[2];
#pragma unroll
    for (int r = 0; r < 2; ++r) uu[r] = *(const float4*)&sm.b.ush[(ty + 16 * r) * LDSW + k];
#pragma unroll
    for (int r = 0; r < 2; ++r) vv[r] = *(const float4*)&sm.b.vsh[(tx + 16 * r) * LDSW + k];
#pragma unroll
    for (int a = 0; a < 2; ++a)
#pragma unroll
      for (int b = 0; b < 2; ++b) {
        acc[a][b] = fmaf(fmaxf(uu[a].x + vv[b].x, 0.f), w.x, acc[a][b]);
        acc[a][b] = fmaf(fmaxf(uu[a].y + vv[b].y, 0.f), w.y, acc[a][b]);
        acc[a][b] = fmaf(fmaxf(uu[a].z + vv[b].z, 0.f), w.z, acc[a][b]);
        acc[a][b] = fmaf(fmaxf(uu[a].w + vv[b].w, 0.f), w.w, acc[a][b]);
      }
  }
  const float bb = b2[0];
#pragma unroll
  for (int a = 0; a < 2; ++a) {
    const int i = bi + ty + 16 * a;
#pragma unroll
    for (int b = 0; b < 2; ++b) {
      const int j = bj + tx + 16 * b;
      if (i != j) out[(size_t)i * NM1 + j - (j > i ? 1 : 0)] = acc[a][b] + bb;
    }
  }
}

extern "C" void kernel_launch(void* const* d_in, const int* in_sizes, int n_in,
                              void* d_out, int out_size, void* d_ws, size_t ws_size,
                              hipStream_t stream) {
  const float* z  = (const float*)d_in[0];
  const float* W1 = (const float*)d_in[1];
  const float* b1 = (const float*)d_in[2];
  const float* W2 = (const float*)d_in[3];
  const float* b2 = (const float*)d_in[4];
  float* U  = (float*)d_ws;
  float* Vb = U + N * H;
  unsigned int* flags = (unsigned int*)(Vb + N * H);
  float* out = (float*)d_out;
  fused_pc3<<<NPROD + (N / TI) * (N / TJ), 256, 0, stream>>>(
      z, W1, b1, W2, b2, U, Vb, flags, out);
}

// Round 10
// 28.119 us; speedup vs baseline: 15.9435x; 15.9435x over previous
//
#include <hip/hip_runtime.h>

#define N 768
#define H 128
#define NM1 767

// ---------------- p1: U = z@W1a^T ; Vb = z@W1b^T + b1 ----------------
// No LDS. z-row reads are block-uniform -> SMEM/s_load pipe; W1 per-lane
// contiguous 512B row stream (L1 reuse 8x); coalesced stores. 256 blocks.
#define P1R 3
__global__ __launch_bounds__(256) void p1_s(
    const float* __restrict__ z, const float* __restrict__ W1,
    const float* __restrict__ b1, float* __restrict__ U, float* __restrict__ Vb) {
  const int t = threadIdx.x;
  const int r0 = blockIdx.x * P1R;
  const int k = t & (H - 1);       // output channel (lanes consecutive -> coalesced stores)
  const int half = t >> 7;         // 0 -> U, 1 -> Vb (wave-uniform)
  const float* __restrict__ wrow = W1 + (size_t)k * (2 * H) + half * H;
  const float* __restrict__ zr0 = z + (size_t)(r0 + 0) * H;
  const float* __restrict__ zr1 = z + (size_t)(r0 + 1) * H;
  const float* __restrict__ zr2 = z + (size_t)(r0 + 2) * H;
  float a0 = 0.f, a1 = 0.f, a2 = 0.f;
#pragma unroll 4                    // cap: full unroll spills (R2 lesson)
  for (int m = 0; m < H; m += 4) {
    const float4 w  = *(const float4*)(wrow + m);   // per-lane VMEM stream
    const float4 z0 = *(const float4*)(zr0 + m);    // uniform -> s_load (SMEM pipe)
    const float4 z1 = *(const float4*)(zr1 + m);
    const float4 z2 = *(const float4*)(zr2 + m);
    a0 = fmaf(w.x, z0.x, a0); a0 = fmaf(w.y, z0.y, a0);
    a0 = fmaf(w.z, z0.z, a0); a0 = fmaf(w.w, z0.w, a0);
    a1 = fmaf(w.x, z1.x, a1); a1 = fmaf(w.y, z1.y, a1);
    a1 = fmaf(w.z, z1.z, a1); a1 = fmaf(w.w, z1.w, a1);
    a2 = fmaf(w.x, z2.x, a2); a2 = fmaf(w.y, z2.y, a2);
    a2 = fmaf(w.z, z2.z, a2); a2 = fmaf(w.w, z2.w, a2);
  }
  const float bias = half ? b1[k] : 0.f;
  float* dst = half ? Vb : U;
  dst[(size_t)(r0 + 0) * H + k] = a0 + bias;
  dst[(size_t)(r0 + 1) * H + k] = a1 + bias;
  dst[(size_t)(r0 + 2) * H + k] = a2 + bias;
}

// ---------------- p2: out[i,j] = sum_k relu(U[i,k]+Vb[j,k]) * w2[k] + b2 ----------------
// Pipe-split: vv from LDS b32 (stride 129 -> bank=(j+k)%32, 2-way=free);
// uu/w2 from global uniform loads (VMEM/SMEM broadcast). Tile 16i x 64j,
// wave = 4i x 64j, acc[4]. 576 blocks, 9 waves/CU. LDS 33 KB.
#define TI 16
#define TJ 64
#define VSTRIDE 129
__global__ __launch_bounds__(256) void p2_v3(
    const float* __restrict__ U, const float* __restrict__ Vb,
    const float* __restrict__ w2, const float* __restrict__ b2,
    float* __restrict__ out) {
  __shared__ float vsh[TJ * VSTRIDE];
  const int t = threadIdx.x;
  const int bi = (blockIdx.x / 12) * TI;
  const int bj = (blockIdx.x % 12) * TJ;
  // stage Vb tile (64 rows x 128): coalesced global read, b32 LDS writes
#pragma unroll
  for (int l = t; l < TJ * (H / 4); l += 256) {
    const int r = l >> 5, c4 = (l & 31) * 4;
    const float4 v = ((const float4*)(Vb + (size_t)(bj + r) * H))[l & 31];
    vsh[r * VSTRIDE + c4 + 0] = v.x;
    vsh[r * VSTRIDE + c4 + 1] = v.y;
    vsh[r * VSTRIDE + c4 + 2] = v.z;
    vsh[r * VSTRIDE + c4 + 3] = v.w;
  }
  __syncthreads();
  const int lj = t & 63;                    // lane -> j column
  const int wr = bi + 4 * (t >> 6);         // wave's first i-row
  const float* __restrict__ u0 = U + (size_t)(wr + 0) * H;
  const float* __restrict__ u1 = U + (size_t)(wr + 1) * H;
  const float* __restrict__ u2 = U + (size_t)(wr + 2) * H;
  const float* __restrict__ u3 = U + (size_t)(wr + 3) * H;
  const float* __restrict__ vrow = vsh + lj * VSTRIDE;
  float acc0 = 0.f, acc1 = 0.f, acc2 = 0.f, acc3 = 0.f;
#pragma unroll 4
  for (int k = 0; k < H; k += 4) {
    const float4 w  = *(const float4*)(w2 + k);   // uniform
    const float4 a0 = *(const float4*)(u0 + k);   // uniform broadcast (VMEM/L1)
    const float4 a1 = *(const float4*)(u1 + k);
    const float4 a2 = *(const float4*)(u2 + k);
    const float4 a3 = *(const float4*)(u3 + k);
    const float v0 = vrow[k + 0], v1 = vrow[k + 1], v2 = vrow[k + 2], v3 = vrow[k + 3];
    acc0 = fmaf(fmaxf(a0.x + v0, 0.f), w.x, acc0);
    acc0 = fmaf(fmaxf(a0.y + v1, 0.f), w.y, acc0);
    acc0 = fmaf(fmaxf(a0.z + v2, 0.f), w.z, acc0);
    acc0 = fmaf(fmaxf(a0.w + v3, 0.f), w.w, acc0);
    acc1 = fmaf(fmaxf(a1.x + v0, 0.f), w.x, acc1);
    acc1 = fmaf(fmaxf(a1.y + v1, 0.f), w.y, acc1);
    acc1 = fmaf(fmaxf(a1.z + v2, 0.f), w.z, acc1);
    acc1 = fmaf(fmaxf(a1.w + v3, 0.f), w.w, acc1);
    acc2 = fmaf(fmaxf(a2.x + v0, 0.f), w.x, acc2);
    acc2 = fmaf(fmaxf(a2.y + v1, 0.f), w.y, acc2);
    acc2 = fmaf(fmaxf(a2.z + v2, 0.f), w.z, acc2);
    acc2 = fmaf(fmaxf(a2.w + v3, 0.f), w.w, acc2);
    acc3 = fmaf(fmaxf(a3.x + v0, 0.f), w.x, acc3);
    acc3 = fmaf(fmaxf(a3.y + v1, 0.f), w.y, acc3);
    acc3 = fmaf(fmaxf(a3.z + v2, 0.f), w.z, acc3);
    acc3 = fmaf(fmaxf(a3.w + v3, 0.f), w.w, acc3);
  }
  const float bb = b2[0];
  const int j = bj + lj;
  {
    const int i = wr + 0;
    if (i != j) out[(size_t)i * NM1 + j - (j > i ? 1 : 0)] = acc0 + bb;
  }
  {
    const int i = wr + 1;
    if (i != j) out[(size_t)i * NM1 + j - (j > i ? 1 : 0)] = acc1 + bb;
  }
  {
    const int i = wr + 2;
    if (i != j) out[(size_t)i * NM1 + j - (j > i ? 1 : 0)] = acc2 + bb;
  }
  {
    const int i = wr + 3;
    if (i != j) out[(size_t)i * NM1 + j - (j > i ? 1 : 0)] = acc3 + bb;
  }
}

extern "C" void kernel_launch(void* const* d_in, const int* in_sizes, int n_in,
                              void* d_out, int out_size, void* d_ws, size_t ws_size,
                              hipStream_t stream) {
  const float* z  = (const float*)d_in[0];
  const float* W1 = (const float*)d_in[1];
  const float* b1 = (const float*)d_in[2];
  const float* W2 = (const float*)d_in[3];
  const float* b2 = (const float*)d_in[4];
  float* U  = (float*)d_ws;
  float* Vb = U + N * H;
  p1_s<<<N / P1R, 256, 0, stream>>>(z, W1, b1, U, Vb);
  p2_v3<<<(N / TI) * (N / TJ), 256, 0, stream>>>(U, Vb, W2, b2, (float*)d_out);
}

// Round 11
// 23.768 us; speedup vs baseline: 18.8628x; 1.1831x over previous
//
#include <hip/hip_runtime.h>

#define N 768
#define H 128
#define NM1 767

// ---------------- p1: R6-verbatim p1_direct (proven) ----------------
#define P1R 4
__global__ __launch_bounds__(256) void p1_direct(
    const float* __restrict__ z, const float* __restrict__ W1,
    const float* __restrict__ b1, float* __restrict__ U, float* __restrict__ Vb) {
  __shared__ __align__(16) float zsh[P1R][H];
  const int t = threadIdx.x;
  const int rbase = blockIdx.x * P1R;
  if (t < P1R * (H / 4)) {
    const int r = t >> 5, c4 = t & 31;
    ((float4*)zsh[r])[c4] = ((const float4*)(z + (size_t)(rbase + r) * H))[c4];
  }
  __syncthreads();
  const int k = t & (H - 1);       // output channel (lanes consecutive -> coalesced stores)
  const int half = t >> 7;         // 0 -> U, 1 -> Vb (wave-uniform)
  const float* __restrict__ wrow = W1 + (size_t)k * (2 * H) + half * H;
  float a0 = 0.f, a1 = 0.f, a2 = 0.f, a3 = 0.f;
#pragma unroll 4                    // cap: full unroll spills (R2 lesson)
  for (int m = 0; m < H; m += 4) {
    const float4 w  = *(const float4*)(wrow + m);       // per-lane own 512B row stream
    const float4 z0 = *(const float4*)&zsh[0][m];       // wave-uniform LDS broadcasts
    const float4 z1 = *(const float4*)&zsh[1][m];
    const float4 z2 = *(const float4*)&zsh[2][m];
    const float4 z3 = *(const float4*)&zsh[3][m];
    a0 = fmaf(w.x, z0.x, a0); a0 = fmaf(w.y, z0.y, a0);
    a0 = fmaf(w.z, z0.z, a0); a0 = fmaf(w.w, z0.w, a0);
    a1 = fmaf(w.x, z1.x, a1); a1 = fmaf(w.y, z1.y, a1);
    a1 = fmaf(w.z, z1.z, a1); a1 = fmaf(w.w, z1.w, a1);
    a2 = fmaf(w.x, z2.x, a2); a2 = fmaf(w.y, z2.y, a2);
    a2 = fmaf(w.z, z2.z, a2); a2 = fmaf(w.w, z2.w, a2);
    a3 = fmaf(w.x, z3.x, a3); a3 = fmaf(w.y, z3.y, a3);
    a3 = fmaf(w.z, z3.z, a3); a3 = fmaf(w.w, z3.w, a3);
  }
  const float bias = half ? b1[k] : 0.f;
  float* dst = half ? Vb : U;
  dst[(size_t)(rbase + 0) * H + k] = a0 + bias;
  dst[(size_t)(rbase + 1) * H + k] = a1 + bias;
  dst[(size_t)(rbase + 2) * H + k] = a2 + bias;
  dst[(size_t)(rbase + 3) * H + k] = a3 + bias;
}

// ---------------- p2: lane=j, wave=4 uniform i-rows; U via SMEM s_load ----------------
// Tile 16i x 64j, grid 576, LDS vsh only (33.8KB -> 4 blk/CU capacity).
// Per wave-kquad: 1 ds_read_b128 (own Vb row) + 4 s_load_dwordx4 (U, forced
// uniform via readfirstlane) + w2 s_load + 48 VALU -> VALU-bound (2.9us/CU model).
#define TI 16
#define TJ 64
#define VST 132   // float row stride: uniform 8-words/bank spread for own-row b128
__global__ __launch_bounds__(256) void p2_smem(
    const float* __restrict__ U, const float* __restrict__ Vb,
    const float* __restrict__ w2, const float* __restrict__ b2,
    float* __restrict__ out) {
  __shared__ __align__(16) float vsh[TJ * VST];
  const int t = threadIdx.x;
  const int bi = (blockIdx.x / 12) * TI;
  const int bj = (blockIdx.x % 12) * TJ;
  // stage Vb tile: 64 rows x 32 float4, b128 writes (row base 132f = 16B-aligned)
#pragma unroll
  for (int l = t; l < TJ * (H / 4); l += 256) {
    const int r = l >> 5, c4 = l & 31;
    *(float4*)&vsh[r * VST + 4 * c4] = ((const float4*)(Vb + (size_t)(bj + r) * H))[c4];
  }
  __syncthreads();
  const int lj = t & 63;                                  // lane -> j column
  const int wv = __builtin_amdgcn_readfirstlane(t >> 6);  // wave id, forced SGPR
  const int wrow = bi + 4 * wv;                           // uniform first i-row
  const float* __restrict__ u0 = U + (size_t)(wrow + 0) * H;  // uniform ptrs -> s_load
  const float* __restrict__ u1 = U + (size_t)(wrow + 1) * H;
  const float* __restrict__ u2 = U + (size_t)(wrow + 2) * H;
  const float* __restrict__ u3 = U + (size_t)(wrow + 3) * H;
  const float* __restrict__ vrow = vsh + lj * VST;
  float acc0 = 0.f, acc1 = 0.f, acc2 = 0.f, acc3 = 0.f;
#pragma unroll 2   // keep SGPR pressure below spill (16 SGPR of U-frags per step)
  for (int k = 0; k < H; k += 4) {
    const float4 w  = *(const float4*)(w2 + k);   // uniform -> s_load
    const float4 a0 = *(const float4*)(u0 + k);   // uniform -> s_load_dwordx4 (SMEM pipe)
    const float4 a1 = *(const float4*)(u1 + k);
    const float4 a2 = *(const float4*)(u2 + k);
    const float4 a3 = *(const float4*)(u3 + k);
    const float4 v  = *(const float4*)(vrow + k); // 1 ds_read_b128, own row
    acc0 = fmaf(fmaxf(a0.x + v.x, 0.f), w.x, acc0);
    acc0 = fmaf(fmaxf(a0.y + v.y, 0.f), w.y, acc0);
    acc0 = fmaf(fmaxf(a0.z + v.z, 0.f), w.z, acc0);
    acc0 = fmaf(fmaxf(a0.w + v.w, 0.f), w.w, acc0);
    acc1 = fmaf(fmaxf(a1.x + v.x, 0.f), w.x, acc1);
    acc1 = fmaf(fmaxf(a1.y + v.y, 0.f), w.y, acc1);
    acc1 = fmaf(fmaxf(a1.z + v.z, 0.f), w.z, acc1);
    acc1 = fmaf(fmaxf(a1.w + v.w, 0.f), w.w, acc1);
    acc2 = fmaf(fmaxf(a2.x + v.x, 0.f), w.x, acc2);
    acc2 = fmaf(fmaxf(a2.y + v.y, 0.f), w.y, acc2);
    acc2 = fmaf(fmaxf(a2.z + v.z, 0.f), w.z, acc2);
    acc2 = fmaf(fmaxf(a2.w + v.w, 0.f), w.w, acc2);
    acc3 = fmaf(fmaxf(a3.x + v.x, 0.f), w.x, acc3);
    acc3 = fmaf(fmaxf(a3.y + v.y, 0.f), w.y, acc3);
    acc3 = fmaf(fmaxf(a3.z + v.z, 0.f), w.z, acc3);
    acc3 = fmaf(fmaxf(a3.w + v.w, 0.f), w.w, acc3);
  }
  const float bb = b2[0];
  const int j = bj + lj;
  {
    const int i = wrow + 0;
    if (i != j) out[(size_t)i * NM1 + j - (j > i ? 1 : 0)] = acc0 + bb;
  }
  {
    const int i = wrow + 1;
    if (i != j) out[(size_t)i * NM1 + j - (j > i ? 1 : 0)] = acc1 + bb;
  }
  {
    const int i = wrow + 2;
    if (i != j) out[(size_t)i * NM1 + j - (j > i ? 1 : 0)] = acc2 + bb;
  }
  {
    const int i = wrow + 3;
    if (i != j) out[(size_t)i * NM1 + j - (j > i ? 1 : 0)] = acc3 + bb;
  }
}

extern "C" void kernel_launch(void* const* d_in, const int* in_sizes, int n_in,
                              void* d_out, int out_size, void* d_ws, size_t ws_size,
                              hipStream_t stream) {
  const float* z  = (const float*)d_in[0];
  const float* W1 = (const float*)d_in[1];
  const float* b1 = (const float*)d_in[2];
  const float* W2 = (const float*)d_in[3];
  const float* b2 = (const float*)d_in[4];
  float* U  = (float*)d_ws;
  float* Vb = U + N * H;
  p1_direct<<<N / P1R, 256, 0, stream>>>(z, W1, b1, U, Vb);
  p2_smem<<<(N / TI) * (N / TJ), 256, 0, stream>>>(U, Vb, W2, b2, (float*)d_out);
}

// Round 12
// 22.256 us; speedup vs baseline: 20.1440x; 1.0679x over previous
//
#include <hip/hip_runtime.h>

#define N 768
#define H 128
#define NM1 767

// ---------------- p1: R6-verbatim p1_direct (proven, ~1.7us) ----------------
#define P1R 4
__global__ __launch_bounds__(256) void p1_direct(
    const float* __restrict__ z, const float* __restrict__ W1,
    const float* __restrict__ b1, float* __restrict__ U, float* __restrict__ Vb) {
  __shared__ __align__(16) float zsh[P1R][H];
  const int t = threadIdx.x;
  const int rbase = blockIdx.x * P1R;
  if (t < P1R * (H / 4)) {
    const int r = t >> 5, c4 = t & 31;
    ((float4*)zsh[r])[c4] = ((const float4*)(z + (size_t)(rbase + r) * H))[c4];
  }
  __syncthreads();
  const int k = t & (H - 1);       // output channel (lanes consecutive -> coalesced stores)
  const int half = t >> 7;         // 0 -> U, 1 -> Vb (wave-uniform)
  const float* __restrict__ wrow = W1 + (size_t)k * (2 * H) + half * H;
  float a0 = 0.f, a1 = 0.f, a2 = 0.f, a3 = 0.f;
#pragma unroll 4                    // cap: full unroll spills (R2 lesson)
  for (int m = 0; m < H; m += 4) {
    const float4 w  = *(const float4*)(wrow + m);       // per-lane own 512B row stream
    const float4 z0 = *(const float4*)&zsh[0][m];       // wave-uniform LDS broadcasts
    const float4 z1 = *(const float4*)&zsh[1][m];
    const float4 z2 = *(const float4*)&zsh[2][m];
    const float4 z3 = *(const float4*)&zsh[3][m];
    a0 = fmaf(w.x, z0.x, a0); a0 = fmaf(w.y, z0.y, a0);
    a0 = fmaf(w.z, z0.z, a0); a0 = fmaf(w.w, z0.w, a0);
    a1 = fmaf(w.x, z1.x, a1); a1 = fmaf(w.y, z1.y, a1);
    a1 = fmaf(w.z, z1.z, a1); a1 = fmaf(w.w, z1.w, a1);
    a2 = fmaf(w.x, z2.x, a2); a2 = fmaf(w.y, z2.y, a2);
    a2 = fmaf(w.z, z2.z, a2); a2 = fmaf(w.w, z2.w, a2);
    a3 = fmaf(w.x, z3.x, a3); a3 = fmaf(w.y, z3.y, a3);
    a3 = fmaf(w.z, z3.z, a3); a3 = fmaf(w.w, z3.w, a3);
  }
  const float bias = half ? b1[k] : 0.f;
  float* dst = half ? Vb : U;
  dst[(size_t)(rbase + 0) * H + k] = a0 + bias;
  dst[(size_t)(rbase + 1) * H + k] = a1 + bias;
  dst[(size_t)(rbase + 2) * H + k] = a2 + bias;
  dst[(size_t)(rbase + 3) * H + k] = a3 + bias;
}

// ---------------- p2: R3-verbatim 48x48 / 3x3 (proven; best LDS-instr ratio at grid>=256) ----------------
#define TI 48
#define TJ 48
#define LDSW (H + 4)  // pad -> row shift of 4 banks: conflict-free/2-way b128 reads
__global__ __launch_bounds__(256) void p2_kernel(
    const float* __restrict__ U, const float* __restrict__ Vb,
    const float* __restrict__ w2, const float* __restrict__ b2,
    float* __restrict__ out) {
  __shared__ __align__(16) float ush[TI * LDSW];
  __shared__ __align__(16) float vsh[TJ * LDSW];
  const int t = threadIdx.x;
  const int bi = (blockIdx.x >> 4) * TI;
  const int bj = (blockIdx.x & 15) * TJ;
#pragma unroll
  for (int l = t; l < TI * (H / 4); l += 256) {
    const int r = l >> 5, c4 = l & 31;
    *(float4*)&ush[r * LDSW + c4 * 4] = ((const float4*)(U  + (size_t)(bi + r) * H))[c4];
    *(float4*)&vsh[r * LDSW + c4 * 4] = ((const float4*)(Vb + (size_t)(bj + r) * H))[c4];
  }
  __syncthreads();
  const int tx = t & 15, ty = t >> 4;
  float acc[3][3] = {};
#pragma unroll 8
  for (int k = 0; k < H; k += 4) {
    const float4 w = *(const float4*)(w2 + k);  // uniform -> scalar load
    float4 uu[3], vv[3];
#pragma unroll
    for (int r = 0; r < 3; ++r) uu[r] = *(const float4*)&ush[(ty + 16 * r) * LDSW + k];
#pragma unroll
    for (int r = 0; r < 3; ++r) vv[r] = *(const float4*)&vsh[(tx + 16 * r) * LDSW + k];
#pragma unroll
    for (int a = 0; a < 3; ++a)
#pragma unroll
      for (int b = 0; b < 3; ++b) {
        acc[a][b] = fmaf(fmaxf(uu[a].x + vv[b].x, 0.f), w.x, acc[a][b]);
        acc[a][b] = fmaf(fmaxf(uu[a].y + vv[b].y, 0.f), w.y, acc[a][b]);
        acc[a][b] = fmaf(fmaxf(uu[a].z + vv[b].z, 0.f), w.z, acc[a][b]);
        acc[a][b] = fmaf(fmaxf(uu[a].w + vv[b].w, 0.f), w.w, acc[a][b]);
      }
  }
  const float bb = b2[0];
#pragma unroll
  for (int a = 0; a < 3; ++a) {
    const int i = bi + ty + 16 * a;
#pragma unroll
    for (int b = 0; b < 3; ++b) {
      const int j = bj + tx + 16 * b;
      if (i != j) out[(size_t)i * NM1 + j - (j > i ? 1 : 0)] = acc[a][b] + bb;
    }
  }
}

extern "C" void kernel_launch(void* const* d_in, const int* in_sizes, int n_in,
                              void* d_out, int out_size, void* d_ws, size_t ws_size,
                              hipStream_t stream) {
  const float* z  = (const float*)d_in[0];
  const float* W1 = (const float*)d_in[1];
  const float* b1 = (const float*)d_in[2];
  const float* W2 = (const float*)d_in[3];
  const float* b2 = (const float*)d_in[4];
  float* U  = (float*)d_ws;
  float* Vb = U + N * H;
  p1_direct<<<N / P1R, 256, 0, stream>>>(z, W1, b1, U, Vb);
  p2_kernel<<<(N / TI) * (N / TJ), 256, 0, stream>>>(U, Vb, W2, b2, (float*)d_out);
}